// Round 10
// baseline (45.504 us; speedup 1.0000x reference)
//
#include <hip/hip_runtime.h>

// LIF neuron forward scan: x [B,N,T] f32, T=256 contiguous (last axis).
// u = u*TAU + x_t; s = (u >= VTH); u = s ? 0 : u; emit s.
// TAU=0.125 (2^-3) -> u*TAU exact -> recurrence bit-matches numpy ref.
//
// R10 = R8 structure + prefetch DEPTH 2 (NT store reverted: R9 proved null).
//  - R8 residual: loads issued and consumed within one chunk body (~600cy)
//    vs ~900cy HBM latency -> ~300cy vmcnt stall per chunk, only 2 waves/SIMD
//    to cover it (grid intrinsically capped at 2048 waves, 1 thread/seq).
//  - Now: body(ch) issues loads for ch+2, lands ch+1 (issued one full body
//    ago). In-flight ~1.7 bodies > HBM latency -> stall gone structurally.
//  - Two named reg sets + fully-unrolled alternating bodies (rule #20:
//    no runtime-indexed reg arrays).

typedef float f32x4 __attribute__((ext_vector_type(4)));

constexpr int   T    = 256;
constexpr int   TV   = T / 4;     // 64 float4 per row
constexpr int   CT   = 32;        // timesteps per chunk
constexpr int   CV   = CT / 4;    // 8 float4 per row-chunk
constexpr int   NCH  = T / CT;    // 8 chunks
constexpr int   SEQB = 64;        // sequences per block (= 1 wave)
constexpr int   RP   = CT + 1;    // padded LDS row stride: scan banks (tid+t)%32
constexpr float TAU  = 0.125f;
constexpr float VTH  = 1.0f;

__global__ __launch_bounds__(64)
void lif_fwd(const f32x4* __restrict__ x, f32x4* __restrict__ out, int nseq) {
    __shared__ float lds[2 * SEQB * RP];   // 16.9 KB -> 8 blocks/CU LDS-ok
    float* bufA = lds;                     // current scan/store buffer
    float* bufB = lds + SEQB * RP;         // landing buffer

    const int tid  = threadIdx.x;          // 0..63
    const int srow = tid >> 3;             // 0..7
    const int k    = tid & 7;              // 0..7
    const int bseq = blockIdx.x * SEQB;

    float u = 0.0f;
    f32x4 rA[CV], rB[CV];

    // ---- prologue: issue chunk0 -> rA, chunk1 -> rB (in order), land chunk0 ----
    #pragma unroll
    for (int j = 0; j < CV; ++j)
        rA[j] = x[(size_t)(bseq + j*8 + srow) * TV + 0*CV + k];
    #pragma unroll
    for (int j = 0; j < CV; ++j)
        rB[j] = x[(size_t)(bseq + j*8 + srow) * TV + 1*CV + k];
    #pragma unroll
    for (int j = 0; j < CV; ++j) {         // waits rA only; rB stays in flight
        float* d = &bufA[(j*8 + srow) * RP + k*4];
        f32x4 v = rA[j];
        d[0]=v.x; d[1]=v.y; d[2]=v.z; d[3]=v.w;
    }
    __syncthreads();

    auto body = [&](int ch, f32x4 (&rNext)[CV], f32x4 (&rLand)[CV]) {
        // issue chunk ch+2 into rNext (those regs were landed last body)
        if (ch + 2 < NCH) {
            #pragma unroll
            for (int j = 0; j < CV; ++j)
                rNext[j] = x[(size_t)(bseq + j*8 + srow) * TV + (ch+2)*CV + k];
        }
        // sequential scan of own row, in place (spike overwrites input)
        #pragma unroll
        for (int t = 0; t < CT; ++t) {
            float xv = bufA[tid * RP + t];
            u = u * TAU + xv;
            bool b = (u >= VTH);
            bufA[tid * RP + t] = b ? 1.0f : 0.0f;
            u = b ? 0.0f : u;
        }
        __syncthreads();
        // cooperative coalesced store of chunk ch
        #pragma unroll
        for (int j = 0; j < CV; ++j) {
            const float* p = &bufA[(j*8 + srow) * RP + k*4];
            f32x4 v; v.x=p[0]; v.y=p[1]; v.z=p[2]; v.w=p[3];
            out[(size_t)(bseq + j*8 + srow) * TV + ch*CV + k] = v;
        }
        // land chunk ch+1 (issued one full body ago) into bufB
        if (ch + 1 < NCH) {
            #pragma unroll
            for (int j = 0; j < CV; ++j) {
                float* d = &bufB[(j*8 + srow) * RP + k*4];
                f32x4 v = rLand[j];
                d[0]=v.x; d[1]=v.y; d[2]=v.z; d[3]=v.w;
            }
        }
        __syncthreads();
        float* tmp = bufA; bufA = bufB; bufB = tmp;
    };

    #pragma unroll
    for (int c2 = 0; c2 < NCH; c2 += 2) {  // fully unrolled: reg sets static
        body(c2 + 0, rA, rB);
        body(c2 + 1, rB, rA);
    }
}

extern "C" void kernel_launch(void* const* d_in, const int* in_sizes, int n_in,
                              void* d_out, int out_size, void* d_ws, size_t ws_size,
                              hipStream_t stream) {
    const float* x = (const float*)d_in[0];
    float* out = (float*)d_out;

    int nseq = in_sizes[0] / T;            // 131072 sequences
    int grid = nseq / SEQB;                // 2048 blocks, exact

    lif_fwd<<<grid, SEQB, 0, stream>>>(
        (const f32x4*)x, (f32x4*)out, nseq);
}